// Round 1
// baseline (722.664 us; speedup 1.0000x reference)
//
#include <hip/hip_runtime.h>

#define N_NODES  100000
#define N_EDGES  1250000
#define N_GRAPHS 1024

// ---------------- embed + linear (16 -> 32) + relu ----------------
__global__ void k_embed_lin(const int* __restrict__ tok,
                            const float* __restrict__ semb,
                            const float* __restrict__ cemb,
                            const float* __restrict__ lw,   // [32,16]
                            const float* __restrict__ lb,   // [32]
                            float* __restrict__ x1) {       // [N,32]
  int i = blockIdx.x * blockDim.x + threadIdx.x;
  if (i >= N_NODES) return;
  int s = tok[2 * i], c = tok[2 * i + 1];
  float e[16];
#pragma unroll
  for (int k = 0; k < 8; ++k) { e[k] = semb[s * 8 + k]; e[8 + k] = cemb[c * 8 + k]; }
#pragma unroll
  for (int o = 0; o < 32; ++o) {
    float acc = lb[o];
#pragma unroll
    for (int k = 0; k < 16; ++k) acc = fmaf(e[k], lw[o * 16 + k], acc);
    x1[(size_t)i * 32 + o] = fmaxf(acc, 0.f);
  }
}

// ---------------- edge scatter: agg[dst] += x[src] ----------------
template <int D>
__global__ void k_scatter(const int* __restrict__ src,
                          const int* __restrict__ dst,
                          const float* __restrict__ x,
                          float* __restrict__ agg) {
  long long idx = (long long)blockIdx.x * blockDim.x + threadIdx.x;
  if (idx >= (long long)N_EDGES * D) return;
  int e = (int)(idx / D);
  int d = (int)(idx % D);
  atomicAdd(&agg[(size_t)dst[e] * D + d], x[(size_t)src[e] * D + d]);
}

// ------- node transform: out = relu(agg@Wrel^T + b + x@Wroot^T) -------
// one thread per (node, out-dim); 64 lanes of a wave share one node.
template <int DIN, bool FUSE_POOL>
__global__ void k_conv(const float* __restrict__ agg,   // [N,DIN]
                       const float* __restrict__ x,     // [N,DIN]
                       const float* __restrict__ wrel,  // [64,DIN]
                       const float* __restrict__ brel,  // [64]
                       const float* __restrict__ wroot, // [64,DIN]
                       const int* __restrict__ batch,
                       float* __restrict__ out) {       // [N,64] or [G,64] sums
  __shared__ float s_wrel[64 * (DIN + 1)];
  __shared__ float s_wroot[64 * (DIN + 1)];
  __shared__ float s_b[64];
  for (int t = threadIdx.x; t < 64 * DIN; t += blockDim.x) {
    int o = t / DIN, k = t - o * DIN;
    s_wrel[o * (DIN + 1) + k] = wrel[t];     // +1 pad: kill 32-way bank conflict
    s_wroot[o * (DIN + 1) + k] = wroot[t];
  }
  if (threadIdx.x < 64) s_b[threadIdx.x] = brel[threadIdx.x];
  __syncthreads();
  int idx = blockIdx.x * blockDim.x + threadIdx.x;
  int i = idx >> 6, o = idx & 63;
  if (i >= N_NODES) return;
  float acc = s_b[o];
#pragma unroll 8
  for (int k = 0; k < DIN; ++k) {
    acc = fmaf(agg[(size_t)i * DIN + k], s_wrel[o * (DIN + 1) + k], acc);
    acc = fmaf(x[(size_t)i * DIN + k], s_wroot[o * (DIN + 1) + k], acc);
  }
  acc = fmaxf(acc, 0.f);
  if (FUSE_POOL) {
    atomicAdd(&out[(size_t)batch[i] * 64 + o], acc);
  } else {
    out[(size_t)i * 64 + o] = acc;
  }
}

// ---------------- per-graph node counts ----------------
__global__ void k_count(const int* __restrict__ batch, int* __restrict__ cnt) {
  int i = blockIdx.x * blockDim.x + threadIdx.x;
  if (i < N_NODES) atomicAdd(&cnt[batch[i]], 1);
}

// ---------------- classifier: out = (sums/cnt)@cls_w^T + cls_b ----------------
__global__ void k_cls(const float* __restrict__ sums, const int* __restrict__ cnt,
                      const float* __restrict__ cw, const float* __restrict__ cb,
                      float* __restrict__ out) {
  int idx = blockIdx.x * blockDim.x + threadIdx.x;
  if (idx >= N_GRAPHS * 10) return;
  int g = idx / 10, c = idx - g * 10;
  float invc = 1.f / fmaxf((float)cnt[g], 1.f);
  float acc = 0.f;
#pragma unroll
  for (int d = 0; d < 64; ++d) acc = fmaf(sums[g * 64 + d], cw[c * 64 + d], acc);
  out[idx] = acc * invc + cb[c];
}

extern "C" void kernel_launch(void* const* d_in, const int* in_sizes, int n_in,
                              void* d_out, int out_size, void* d_ws, size_t ws_size,
                              hipStream_t stream) {
  const int*   tok    = (const int*)d_in[0];
  const int*   eidx   = (const int*)d_in[1];
  const int*   batch  = (const int*)d_in[2];
  const float* semb   = (const float*)d_in[3];
  const float* cemb   = (const float*)d_in[4];
  const float* lw     = (const float*)d_in[5];
  const float* lb     = (const float*)d_in[6];
  const float* w1rel  = (const float*)d_in[7];
  const float* b1     = (const float*)d_in[8];
  const float* w1root = (const float*)d_in[9];
  const float* w2rel  = (const float*)d_in[10];
  const float* b2     = (const float*)d_in[11];
  const float* w2root = (const float*)d_in[12];
  const float* cw     = (const float*)d_in[13];
  const float* cb     = (const float*)d_in[14];
  const int* src = eidx;
  const int* dst = eidx + N_EDGES;

  char* ws = (char*)d_ws;
  float* x1   = (float*)ws;                                            // N*32
  float* x2   = (float*)(ws + (size_t)N_NODES * 32 * 4);               // N*64
  float* agg  = (float*)(ws + (size_t)N_NODES * (32 + 64) * 4);        // N*64
  float* sums = (float*)(ws + (size_t)N_NODES * (32 + 64 + 64) * 4);   // G*64
  int*   cnt  = (int*)((char*)sums + (size_t)N_GRAPHS * 64 * 4);       // G

  // zero conv1 aggregation buffer + pooled sums + counts
  hipMemsetAsync(agg, 0, (size_t)N_NODES * 32 * 4, stream);
  hipMemsetAsync(sums, 0, (size_t)N_GRAPHS * 64 * 4 + (size_t)N_GRAPHS * 4, stream);

  k_embed_lin<<<(N_NODES + 255) / 256, 256, 0, stream>>>(tok, semb, cemb, lw, lb, x1);

  k_scatter<32><<<(int)(((long long)N_EDGES * 32 + 255) / 256), 256, 0, stream>>>(src, dst, x1, agg);
  k_conv<32, false><<<(N_NODES * 64 + 255) / 256, 256, 0, stream>>>(agg, x1, w1rel, b1, w1root,
                                                                    nullptr, x2);

  hipMemsetAsync(agg, 0, (size_t)N_NODES * 64 * 4, stream);
  k_scatter<64><<<(int)(((long long)N_EDGES * 64 + 255) / 256), 256, 0, stream>>>(src, dst, x2, agg);

  k_count<<<(N_NODES + 255) / 256, 256, 0, stream>>>(batch, cnt);
  k_conv<64, true><<<(N_NODES * 64 + 255) / 256, 256, 0, stream>>>(agg, x2, w2rel, b2, w2root,
                                                                   batch, sums);

  k_cls<<<(N_GRAPHS * 10 + 255) / 256, 256, 0, stream>>>(sums, cnt, cw, cb, (float*)d_out);
}

// Round 2
// 677.402 us; speedup vs baseline: 1.0668x; 1.0668x over previous
//
#include <hip/hip_runtime.h>

#define N_NODES  100000
#define N_EDGES  1250000
#define N_GRAPHS 1024
#define SCAN_BLK 1024
#define N_SCAN_BLOCKS ((N_NODES + SCAN_BLK - 1) / SCAN_BLK)   // 98

// ---------------- embed + linear (16 -> 32) + relu ----------------
__global__ void k_embed_lin(const int* __restrict__ tok,
                            const float* __restrict__ semb,
                            const float* __restrict__ cemb,
                            const float* __restrict__ lw,   // [32,16]
                            const float* __restrict__ lb,   // [32]
                            float* __restrict__ x1) {       // [N,32]
  int i = blockIdx.x * blockDim.x + threadIdx.x;
  if (i >= N_NODES) return;
  int s = tok[2 * i], c = tok[2 * i + 1];
  float e[16];
#pragma unroll
  for (int k = 0; k < 8; ++k) { e[k] = semb[s * 8 + k]; e[8 + k] = cemb[c * 8 + k]; }
#pragma unroll
  for (int o = 0; o < 32; ++o) {
    float acc = lb[o];
#pragma unroll
    for (int k = 0; k < 16; ++k) acc = fmaf(e[k], lw[o * 16 + k], acc);
    x1[(size_t)i * 32 + o] = fmaxf(acc, 0.f);
  }
}

// ---------------- CSR build: histogram -> scan -> fill ----------------
__global__ void k_hist(const int* __restrict__ dst, int* __restrict__ deg) {
  int e = blockIdx.x * blockDim.x + threadIdx.x;
  if (e < N_EDGES) atomicAdd(&deg[dst[e]], 1);
}

__global__ void k_scan1(const int* __restrict__ deg, int* __restrict__ incl,
                        int* __restrict__ bsum) {
  __shared__ int s[SCAN_BLK];
  int i = blockIdx.x * SCAN_BLK + threadIdx.x;
  s[threadIdx.x] = (i < N_NODES) ? deg[i] : 0;
  __syncthreads();
  for (int off = 1; off < SCAN_BLK; off <<= 1) {
    int t = (threadIdx.x >= off) ? s[threadIdx.x - off] : 0;
    __syncthreads();
    s[threadIdx.x] += t;
    __syncthreads();
  }
  if (i < N_NODES) incl[i] = s[threadIdx.x];
  if (threadIdx.x == SCAN_BLK - 1) bsum[blockIdx.x] = s[threadIdx.x];
}

__global__ void k_scan2(const int* __restrict__ bsum, int* __restrict__ boff) {
  if (threadIdx.x == 0) {
    int acc = 0;
    for (int b = 0; b < N_SCAN_BLOCKS; ++b) { boff[b] = acc; acc += bsum[b]; }
  }
}

__global__ void k_scan3(const int* __restrict__ incl, const int* __restrict__ deg,
                        const int* __restrict__ boff,
                        int* __restrict__ rowstart, int* __restrict__ cursor) {
  int i = blockIdx.x * blockDim.x + threadIdx.x;
  if (i >= N_NODES) return;
  int excl = incl[i] - deg[i] + boff[i >> 10];
  rowstart[i] = excl;
  cursor[i] = excl;
}

__global__ void k_fill(const int* __restrict__ src, const int* __restrict__ dst,
                       int* __restrict__ cursor, int* __restrict__ esrc) {
  int e = blockIdx.x * blockDim.x + threadIdx.x;
  if (e >= N_EDGES) return;
  int pos = atomicAdd(&cursor[dst[e]], 1);
  esrc[pos] = src[e];
}

// ------- fused gather-aggregate + GraphConv transform -------
// One wave (64 lanes) per destination node. Lanes = input dims, so each
// incoming edge is a single coalesced 128/256B row load of x[src].
template <int DIN, bool FUSE_POOL>
__global__ void k_fused_conv(const int* __restrict__ rowstart,
                             const int* __restrict__ deg,
                             const int* __restrict__ esrc,
                             const float* __restrict__ x,      // [N,DIN]
                             const float* __restrict__ wrel,   // [64,DIN]
                             const float* __restrict__ brel,   // [64]
                             const float* __restrict__ wroot,  // [64,DIN]
                             const int* __restrict__ batch,
                             float* __restrict__ out) {        // [N,64] or [G,64]
  constexpr int PAD = DIN + 1;                 // (o+k)%32 banks -> 2-way max (free)
  __shared__ float s_wrel[64 * PAD];
  __shared__ float s_wroot[64 * PAD];
  __shared__ float s_b[64];
  __shared__ float s_agg[4][DIN];
  __shared__ float s_x[4][DIN];
  for (int t = threadIdx.x; t < 64 * DIN; t += blockDim.x) {
    int o = t / DIN, k = t - o * DIN;
    s_wrel[o * PAD + k] = wrel[t];
    s_wroot[o * PAD + k] = wroot[t];
  }
  if (threadIdx.x < 64) s_b[threadIdx.x] = brel[threadIdx.x];

  const int wave = threadIdx.x >> 6;
  const int lane = threadIdx.x & 63;
  const int node = blockIdx.x * (blockDim.x >> 6) + wave;   // grid sized exactly
  constexpr int SUBS = 64 / DIN;               // 2 for DIN=32, 1 for DIN=64
  const int sub = lane / DIN;
  const int k = lane % DIN;

  float a = 0.f;
  const int rs = rowstart[node];
  const int dg = deg[node];
  for (int e = sub; e < dg; e += SUBS)
    a += x[(size_t)esrc[rs + e] * DIN + k];
  if (SUBS == 2) a += __shfl_xor(a, 32);
  if (sub == 0) {
    s_agg[wave][k] = a;
    s_x[wave][k] = x[(size_t)node * DIN + k];
  }
  __syncthreads();

  const int o = lane;
  float acc = s_b[o];
#pragma unroll
  for (int kk = 0; kk < DIN; ++kk) {
    acc = fmaf(s_agg[wave][kk], s_wrel[o * PAD + kk], acc);
    acc = fmaf(s_x[wave][kk], s_wroot[o * PAD + kk], acc);
  }
  acc = fmaxf(acc, 0.f);
  if (FUSE_POOL) {
    atomicAdd(&out[(size_t)batch[node] * 64 + o], acc);
  } else {
    out[(size_t)node * 64 + o] = acc;
  }
}

// ---------------- per-graph node counts ----------------
__global__ void k_count(const int* __restrict__ batch, int* __restrict__ cnt) {
  int i = blockIdx.x * blockDim.x + threadIdx.x;
  if (i < N_NODES) atomicAdd(&cnt[batch[i]], 1);
}

// ---------------- classifier ----------------
__global__ void k_cls(const float* __restrict__ sums, const int* __restrict__ cnt,
                      const float* __restrict__ cw, const float* __restrict__ cb,
                      float* __restrict__ out) {
  int idx = blockIdx.x * blockDim.x + threadIdx.x;
  if (idx >= N_GRAPHS * 10) return;
  int g = idx / 10, c = idx - g * 10;
  float invc = 1.f / fmaxf((float)cnt[g], 1.f);
  float acc = 0.f;
#pragma unroll
  for (int d = 0; d < 64; ++d) acc = fmaf(sums[g * 64 + d], cw[c * 64 + d], acc);
  out[idx] = acc * invc + cb[c];
}

extern "C" void kernel_launch(void* const* d_in, const int* in_sizes, int n_in,
                              void* d_out, int out_size, void* d_ws, size_t ws_size,
                              hipStream_t stream) {
  const int*   tok    = (const int*)d_in[0];
  const int*   eidx   = (const int*)d_in[1];
  const int*   batch  = (const int*)d_in[2];
  const float* semb   = (const float*)d_in[3];
  const float* cemb   = (const float*)d_in[4];
  const float* lw     = (const float*)d_in[5];
  const float* lb     = (const float*)d_in[6];
  const float* w1rel  = (const float*)d_in[7];
  const float* b1     = (const float*)d_in[8];
  const float* w1root = (const float*)d_in[9];
  const float* w2rel  = (const float*)d_in[10];
  const float* b2     = (const float*)d_in[11];
  const float* w2root = (const float*)d_in[12];
  const float* cw     = (const float*)d_in[13];
  const float* cb     = (const float*)d_in[14];
  const int* src = eidx;
  const int* dst = eidx + N_EDGES;

  char* p = (char*)d_ws;
  float* x1      = (float*)p;  p += (size_t)N_NODES * 32 * 4;
  float* x2      = (float*)p;  p += (size_t)N_NODES * 64 * 4;
  int*   degv    = (int*)p;    p += (size_t)N_NODES * 4;
  int*   incl    = (int*)p;    p += (size_t)N_NODES * 4;
  int*   rowst   = (int*)p;    p += (size_t)N_NODES * 4;
  int*   cursor  = (int*)p;    p += (size_t)N_NODES * 4;
  int*   bsum    = (int*)p;    p += 128 * 4;
  int*   boff    = (int*)p;    p += 128 * 4;
  int*   esrc    = (int*)p;    p += (size_t)N_EDGES * 4;
  float* sums    = (float*)p;  p += (size_t)N_GRAPHS * 64 * 4;
  int*   cnt     = (int*)p;    p += (size_t)N_GRAPHS * 4;

  hipMemsetAsync(degv, 0, (size_t)N_NODES * 4, stream);
  hipMemsetAsync(sums, 0, (size_t)N_GRAPHS * 64 * 4 + (size_t)N_GRAPHS * 4, stream);

  k_embed_lin<<<(N_NODES + 255) / 256, 256, 0, stream>>>(tok, semb, cemb, lw, lb, x1);

  // CSR of incoming edges (shared by both conv layers)
  k_hist<<<(N_EDGES + 255) / 256, 256, 0, stream>>>(dst, degv);
  k_scan1<<<N_SCAN_BLOCKS, SCAN_BLK, 0, stream>>>(degv, incl, bsum);
  k_scan2<<<1, 64, 0, stream>>>(bsum, boff);
  k_scan3<<<(N_NODES + 255) / 256, 256, 0, stream>>>(incl, degv, boff, rowst, cursor);
  k_fill<<<(N_EDGES + 255) / 256, 256, 0, stream>>>(src, dst, cursor, esrc);

  // conv1: x1[N,32] -> x2[N,64]   (100000 nodes = 25000 blocks * 4 waves exactly)
  k_fused_conv<32, false><<<N_NODES / 4, 256, 0, stream>>>(rowst, degv, esrc, x1,
                                                           w1rel, b1, w1root, nullptr, x2);
  k_count<<<(N_NODES + 255) / 256, 256, 0, stream>>>(batch, cnt);
  // conv2 + fused mean-pool sums: x2[N,64] -> sums[G,64]
  k_fused_conv<64, true><<<N_NODES / 4, 256, 0, stream>>>(rowst, degv, esrc, x2,
                                                          w2rel, b2, w2root, batch, sums);

  k_cls<<<(N_GRAPHS * 10 + 255) / 256, 256, 0, stream>>>(sums, cnt, cw, cb, (float*)d_out);
}

// Round 3
// 414.732 us; speedup vs baseline: 1.7425x; 1.6333x over previous
//
#include <hip/hip_runtime.h>

#define N_NODES  100000
#define N_EDGES  1250000
#define N_GRAPHS 1024
#define SCAN_BLK 1024
#define N_SCAN_BLOCKS ((N_NODES + SCAN_BLK - 1) / SCAN_BLK)   // 98

// ---------------- embed + linear (16 -> 32) + relu ----------------
__global__ void k_embed_lin(const int* __restrict__ tok,
                            const float* __restrict__ semb,
                            const float* __restrict__ cemb,
                            const float* __restrict__ lw,   // [32,16]
                            const float* __restrict__ lb,   // [32]
                            float* __restrict__ x1) {       // [N,32]
  int i = blockIdx.x * blockDim.x + threadIdx.x;
  if (i >= N_NODES) return;
  int s = tok[2 * i], c = tok[2 * i + 1];
  float e[16];
#pragma unroll
  for (int k = 0; k < 8; ++k) { e[k] = semb[s * 8 + k]; e[8 + k] = cemb[c * 8 + k]; }
  float o_[32];
#pragma unroll
  for (int o = 0; o < 32; ++o) {
    float acc = lb[o];
#pragma unroll
    for (int k = 0; k < 16; ++k) acc = fmaf(e[k], lw[o * 16 + k], acc);
    o_[o] = fmaxf(acc, 0.f);
  }
  float4* dst4 = (float4*)(x1 + (size_t)i * 32);
#pragma unroll
  for (int q = 0; q < 8; ++q)
    dst4[q] = make_float4(o_[4 * q], o_[4 * q + 1], o_[4 * q + 2], o_[4 * q + 3]);
}

// ---------------- CSR build: histogram -> scan -> fill ----------------
__global__ void k_hist(const int* __restrict__ dst, int* __restrict__ deg) {
  int e = blockIdx.x * blockDim.x + threadIdx.x;
  if (e < N_EDGES) atomicAdd(&deg[dst[e]], 1);
}

__global__ void k_scan1(const int* __restrict__ deg, int* __restrict__ incl,
                        int* __restrict__ bsum) {
  __shared__ int s[SCAN_BLK];
  int i = blockIdx.x * SCAN_BLK + threadIdx.x;
  s[threadIdx.x] = (i < N_NODES) ? deg[i] : 0;
  __syncthreads();
  for (int off = 1; off < SCAN_BLK; off <<= 1) {
    int t = (threadIdx.x >= off) ? s[threadIdx.x - off] : 0;
    __syncthreads();
    s[threadIdx.x] += t;
    __syncthreads();
  }
  if (i < N_NODES) incl[i] = s[threadIdx.x];
  if (threadIdx.x == SCAN_BLK - 1) bsum[blockIdx.x] = s[threadIdx.x];
}

__global__ void k_scan2(const int* __restrict__ bsum, int* __restrict__ boff) {
  if (threadIdx.x == 0) {
    int acc = 0;
    for (int b = 0; b < N_SCAN_BLOCKS; ++b) { boff[b] = acc; acc += bsum[b]; }
  }
}

__global__ void k_scan3(const int* __restrict__ incl, const int* __restrict__ deg,
                        const int* __restrict__ boff,
                        int* __restrict__ rowstart, int* __restrict__ cursor) {
  int i = blockIdx.x * blockDim.x + threadIdx.x;
  if (i >= N_NODES) return;
  int excl = incl[i] - deg[i] + boff[i >> 10];
  rowstart[i] = excl;
  cursor[i] = excl;
}

__global__ void k_fill(const int* __restrict__ src, const int* __restrict__ dst,
                       int* __restrict__ cursor, int* __restrict__ esrc) {
  int e = blockIdx.x * blockDim.x + threadIdx.x;
  if (e >= N_EDGES) return;
  int pos = atomicAdd(&cursor[dst[e]], 1);
  esrc[pos] = src[e];
}

// ---------------- batched gather: agg[i] = sum_{j->i} x[j] ----------------
// One wave per node. Wave loads up to 64 edge indices in ONE coalesced load,
// then 64/(DIN/4) lane-groups each fetch a float4 row-slice; 16 edges' loads
// issued per superstep (independent) -> ~2 latency exposures per node.
template <int DIN>
__global__ void __launch_bounds__(256, 4)
k_gather(const int* __restrict__ rowstart,
         const int* __restrict__ deg,
         const int* __restrict__ esrc,
         const float* __restrict__ x,     // [N,DIN]
         float* __restrict__ agg) {       // [N,DIN]
  constexpr int LPG = DIN / 4;            // lanes per edge-group: 8 / 16
  constexpr int GROUPS = 64 / LPG;        // 8 (DIN=32) / 4 (DIN=64)
  constexpr int STEP = 16;                // edges per superstep
  constexpr int UNR = STEP / GROUPS;      // 2 / 4
  const int lane = threadIdx.x & 63;
  const int node = blockIdx.x * (blockDim.x >> 6) + (threadIdx.x >> 6);
  if (node >= N_NODES) return;
  const int sub = lane / LPG;
  const int lg = lane % LPG;
  const int rs = rowstart[node];
  const int dg = deg[node];
  float4 acc = make_float4(0.f, 0.f, 0.f, 0.f);
  for (int base = 0; base < dg; base += 64) {
    const int lim = min(dg - base, 64);
    int myi = 0;
    if (lane < lim) myi = esrc[rs + base + lane];
    for (int j = 0; j < lim; j += STEP) {
      float4 r[UNR];
      int e[UNR];
#pragma unroll
      for (int u = 0; u < UNR; ++u) {
        e[u] = j + u * GROUPS + sub;                      // always < 64
        int s = __shfl(myi, e[u]);
        r[u] = *((const float4*)(x + (size_t)s * DIN) + lg);
      }
#pragma unroll
      for (int u = 0; u < UNR; ++u) {
        if (e[u] < lim) {
          acc.x += r[u].x; acc.y += r[u].y; acc.z += r[u].z; acc.w += r[u].w;
        }
      }
    }
  }
#pragma unroll
  for (int off = LPG; off < 64; off <<= 1) {
    acc.x += __shfl_xor(acc.x, off);
    acc.y += __shfl_xor(acc.y, off);
    acc.z += __shfl_xor(acc.z, off);
    acc.w += __shfl_xor(acc.w, off);
  }
  if (sub == 0)
    *((float4*)(agg + (size_t)node * DIN) + lg) = acc;
}

// ------- transform: out = relu(agg@Wrel^T + b + x@Wroot^T), weights in VGPRs -------
// Grid-stride over nodes, one wave per node per iteration. Lane o owns output o;
// weight rows live in registers; agg/x rows are wave-uniform broadcast loads.
template <int DIN, bool FUSE_POOL>
__global__ void __launch_bounds__(256, 2)
k_transform(const float* __restrict__ agg,    // [N,DIN]
            const float* __restrict__ x,      // [N,DIN]
            const float* __restrict__ wrel,   // [64,DIN]
            const float* __restrict__ brel,   // [64]
            const float* __restrict__ wroot,  // [64,DIN]
            const int* __restrict__ batch,
            float* __restrict__ out) {        // [N,64] or [G,64] sums
  const int lane = threadIdx.x & 63;
  const int wv = __builtin_amdgcn_readfirstlane((int)(threadIdx.x >> 6));
  const int wid = blockIdx.x * (blockDim.x >> 6) + wv;
  const int nwaves = (gridDim.x * blockDim.x) >> 6;

  float wr[DIN], wo[DIN];
#pragma unroll
  for (int q = 0; q < DIN / 4; ++q) {
    float4 a = *((const float4*)(wrel + (size_t)lane * DIN) + q);
    wr[4 * q] = a.x; wr[4 * q + 1] = a.y; wr[4 * q + 2] = a.z; wr[4 * q + 3] = a.w;
    float4 b = *((const float4*)(wroot + (size_t)lane * DIN) + q);
    wo[4 * q] = b.x; wo[4 * q + 1] = b.y; wo[4 * q + 2] = b.z; wo[4 * q + 3] = b.w;
  }
  const float bias = brel[lane];

  for (int node = wid; node < N_NODES; node += nwaves) {
    const float4* ar = (const float4*)(agg + (size_t)node * DIN);
    const float4* xr = (const float4*)(x + (size_t)node * DIN);
    float acc = bias;
#pragma unroll
    for (int q = 0; q < DIN / 4; ++q) {
      float4 a = ar[q];                       // wave-uniform -> broadcast
      float4 b = xr[q];
      acc = fmaf(a.x, wr[4 * q], acc);
      acc = fmaf(a.y, wr[4 * q + 1], acc);
      acc = fmaf(a.z, wr[4 * q + 2], acc);
      acc = fmaf(a.w, wr[4 * q + 3], acc);
      acc = fmaf(b.x, wo[4 * q], acc);
      acc = fmaf(b.y, wo[4 * q + 1], acc);
      acc = fmaf(b.z, wo[4 * q + 2], acc);
      acc = fmaf(b.w, wo[4 * q + 3], acc);
    }
    acc = fmaxf(acc, 0.f);
    if (FUSE_POOL) {
      atomicAdd(&out[(size_t)batch[node] * 64 + lane], acc);
    } else {
      out[(size_t)node * 64 + lane] = acc;
    }
  }
}

// ---------------- per-graph node counts ----------------
__global__ void k_count(const int* __restrict__ batch, int* __restrict__ cnt) {
  int i = blockIdx.x * blockDim.x + threadIdx.x;
  if (i < N_NODES) atomicAdd(&cnt[batch[i]], 1);
}

// ---------------- classifier ----------------
__global__ void k_cls(const float* __restrict__ sums, const int* __restrict__ cnt,
                      const float* __restrict__ cw, const float* __restrict__ cb,
                      float* __restrict__ out) {
  int idx = blockIdx.x * blockDim.x + threadIdx.x;
  if (idx >= N_GRAPHS * 10) return;
  int g = idx / 10, c = idx - g * 10;
  float invc = 1.f / fmaxf((float)cnt[g], 1.f);
  float acc = 0.f;
#pragma unroll
  for (int d = 0; d < 64; ++d) acc = fmaf(sums[g * 64 + d], cw[c * 64 + d], acc);
  out[idx] = acc * invc + cb[c];
}

extern "C" void kernel_launch(void* const* d_in, const int* in_sizes, int n_in,
                              void* d_out, int out_size, void* d_ws, size_t ws_size,
                              hipStream_t stream) {
  const int*   tok    = (const int*)d_in[0];
  const int*   eidx   = (const int*)d_in[1];
  const int*   batch  = (const int*)d_in[2];
  const float* semb   = (const float*)d_in[3];
  const float* cemb   = (const float*)d_in[4];
  const float* lw     = (const float*)d_in[5];
  const float* lb     = (const float*)d_in[6];
  const float* w1rel  = (const float*)d_in[7];
  const float* b1     = (const float*)d_in[8];
  const float* w1root = (const float*)d_in[9];
  const float* w2rel  = (const float*)d_in[10];
  const float* b2     = (const float*)d_in[11];
  const float* w2root = (const float*)d_in[12];
  const float* cw     = (const float*)d_in[13];
  const float* cb     = (const float*)d_in[14];
  const int* src = eidx;
  const int* dst = eidx + N_EDGES;

  char* p = (char*)d_ws;
  float* x1      = (float*)p;  p += (size_t)N_NODES * 32 * 4;
  float* x2      = (float*)p;  p += (size_t)N_NODES * 64 * 4;
  float* aggb    = (float*)p;  p += (size_t)N_NODES * 64 * 4;
  int*   degv    = (int*)p;    p += (size_t)N_NODES * 4;
  int*   incl    = (int*)p;    p += (size_t)N_NODES * 4;
  int*   rowst   = (int*)p;    p += (size_t)N_NODES * 4;
  int*   cursor  = (int*)p;    p += (size_t)N_NODES * 4;
  int*   bsum    = (int*)p;    p += 128 * 4;
  int*   boff    = (int*)p;    p += 128 * 4;
  int*   esrc    = (int*)p;    p += (size_t)N_EDGES * 4;
  float* sums    = (float*)p;  p += (size_t)N_GRAPHS * 64 * 4;
  int*   cnt     = (int*)p;    p += (size_t)N_GRAPHS * 4;

  hipMemsetAsync(degv, 0, (size_t)N_NODES * 4, stream);
  hipMemsetAsync(sums, 0, (size_t)N_GRAPHS * 64 * 4 + (size_t)N_GRAPHS * 4, stream);

  k_embed_lin<<<(N_NODES + 255) / 256, 256, 0, stream>>>(tok, semb, cemb, lw, lb, x1);

  // CSR of incoming edges (shared by both conv layers)
  k_hist<<<(N_EDGES + 255) / 256, 256, 0, stream>>>(dst, degv);
  k_scan1<<<N_SCAN_BLOCKS, SCAN_BLK, 0, stream>>>(degv, incl, bsum);
  k_scan2<<<1, 64, 0, stream>>>(bsum, boff);
  k_scan3<<<(N_NODES + 255) / 256, 256, 0, stream>>>(incl, degv, boff, rowst, cursor);
  k_fill<<<(N_EDGES + 255) / 256, 256, 0, stream>>>(src, dst, cursor, esrc);

  // conv1: gather x1 -> agg, transform -> x2
  k_gather<32><<<N_NODES / 4, 256, 0, stream>>>(rowst, degv, esrc, x1, aggb);
  k_transform<32, false><<<512, 256, 0, stream>>>(aggb, x1, w1rel, b1, w1root, nullptr, x2);

  // conv2: gather x2 -> agg, transform + fused mean-pool sums
  k_gather<64><<<N_NODES / 4, 256, 0, stream>>>(rowst, degv, esrc, x2, aggb);
  k_count<<<(N_NODES + 255) / 256, 256, 0, stream>>>(batch, cnt);
  k_transform<64, true><<<512, 256, 0, stream>>>(aggb, x2, w2rel, b2, w2root, batch, sums);

  k_cls<<<(N_GRAPHS * 10 + 255) / 256, 256, 0, stream>>>(sums, cnt, cw, cb, (float*)d_out);
}